// Round 1
// baseline (1609.531 us; speedup 1.0000x reference)
//
#include <hip/hip_runtime.h>
#include <hip/hip_bf16.h>
#include <cstddef>

#define N_NODES 50000
#define N_EDGES 1600000
#define D 128
#define TWO_D 256
#define L 3
#define EPS 1e-7f
#define LN_EPS 1e-5f

// ---------------- CSR build ----------------

__global__ __launch_bounds__(256) void hist_kernel(const int* __restrict__ ei, int* __restrict__ deg) {
    int idx = blockIdx.x * blockDim.x + threadIdx.x;
    int stride = gridDim.x * blockDim.x;
    for (int e = idx; e < N_EDGES; e += stride)
        atomicAdd(&deg[ei[N_EDGES + e]], 1);
}

__global__ __launch_bounds__(1024) void scan_kernel(const int* __restrict__ deg, int* __restrict__ rowptr) {
    __shared__ int s[1024];
    __shared__ int carry_s;
    int t = threadIdx.x;
    if (t == 0) { carry_s = 0; rowptr[0] = 0; }
    __syncthreads();
    for (int base = 0; base < N_NODES; base += 1024) {
        int i = base + t;
        int v = (i < N_NODES) ? deg[i] : 0;
        s[t] = v;
        __syncthreads();
        // Hillis-Steele inclusive scan
        for (int off = 1; off < 1024; off <<= 1) {
            int u = (t >= off) ? s[t - off] : 0;
            __syncthreads();
            s[t] += u;
            __syncthreads();
        }
        if (i < N_NODES) rowptr[i + 1] = carry_s + s[t];
        __syncthreads();
        if (t == 0) carry_s += s[1023];
        __syncthreads();
    }
}

__global__ __launch_bounds__(256) void scatter_kernel(const int* __restrict__ ei, const int* __restrict__ rowptr,
                                                      int* __restrict__ cursor, int* __restrict__ eids,
                                                      int* __restrict__ srcp) {
    int idx = blockIdx.x * blockDim.x + threadIdx.x;
    int stride = gridDim.x * blockDim.x;
    for (int e = idx; e < N_EDGES; e += stride) {
        int dn = ei[N_EDGES + e];
        int pos = atomicAdd(&cursor[dn], 1);
        int slot = rowptr[dn] + pos;
        eids[slot] = e;
        srcp[slot] = ei[e];
    }
}

// ---------------- LayerNorm + ReLU ----------------

__global__ __launch_bounds__(256) void ln_relu_kernel(const float* __restrict__ h, const float* __restrict__ scale,
                                                      const float* __restrict__ bias, float* __restrict__ out) {
    int wid = threadIdx.x >> 6, lane = threadIdx.x & 63;
    int row = blockIdx.x * 4 + wid;
    if (row >= N_NODES) return;
    float2 hv = *(const float2*)(h + (size_t)row * D + lane * 2);
    float sum = hv.x + hv.y;
    for (int off = 32; off; off >>= 1) sum += __shfl_xor(sum, off);
    float mu = sum * (1.0f / D);
    float dx = hv.x - mu, dy = hv.y - mu;
    float vs = dx * dx + dy * dy;
    for (int off = 32; off; off >>= 1) vs += __shfl_xor(vs, off);
    float r = rsqrtf(vs * (1.0f / D) + LN_EPS);
    float2 sc = *(const float2*)(scale + lane * 2);
    float2 bi = *(const float2*)(bias + lane * 2);
    float2 o;
    o.x = fmaxf(dx * r * sc.x + bi.x, 0.f);
    o.y = fmaxf(dy * r * sc.y + bi.y, 0.f);
    *(float2*)(out + (size_t)row * D + lane * 2) = o;
}

// ---------------- Softmax aggregation (one wave per dst node) ----------------
// aggr = sum(e*msg)/sum(e), e = exp(beta*msg).  Shift-invariance makes the
// segment_max pass unnecessary; msg <= ~10 so exp() is safe in f32.

__global__ __launch_bounds__(256) void aggregate_kernel(const float* __restrict__ hn, const float* __restrict__ ea,
                                                        const int* __restrict__ rowptr, const int* __restrict__ eids,
                                                        const int* __restrict__ srcp, const float* __restrict__ beta,
                                                        int layer, float* __restrict__ pre) {
    int wid = threadIdx.x >> 6, lane = threadIdx.x & 63;
    int d = blockIdx.x * 4 + wid;
    if (d >= N_NODES) return;
    float bet = beta[layer];
    int j0 = rowptr[d], j1 = rowptr[d + 1];
    float se0 = 0.f, se1 = 0.f, sm0 = 0.f, sm1 = 0.f;
    for (int j = j0; j < j1; ++j) {
        int e = eids[j];
        int s = srcp[j];
        float2 hv = *(const float2*)(hn + (size_t)s * D + lane * 2);
        float2 av = *(const float2*)(ea + (size_t)e * D + lane * 2);
        float m0 = fmaxf(hv.x + av.x, 0.f) + EPS;
        float m1 = fmaxf(hv.y + av.y, 0.f) + EPS;
        float e0 = __expf(bet * m0);
        float e1 = __expf(bet * m1);
        se0 += e0; sm0 += e0 * m0;
        se1 += e1; sm1 += e1 * m1;
    }
    float a0 = se0 > 0.f ? sm0 / se0 : 0.f;
    float a1 = se1 > 0.f ? sm1 / se1 : 0.f;
    float2 hv = *(const float2*)(hn + (size_t)d * D + lane * 2);
    float2 o;
    o.x = hv.x + a0;
    o.y = hv.y + a1;
    *(float2*)(pre + (size_t)d * D + lane * 2) = o;
}

// ---------------- MLP GEMMs (f32 vector, weights L1-cached) ----------------

// hid[N,256] = relu(in[N,128] @ W[128,256] + b)
__global__ __launch_bounds__(256) void gemm1_kernel(const float* __restrict__ in, const float* __restrict__ W,
                                                    const float* __restrict__ b, float* __restrict__ out) {
    __shared__ float xs[32][D];
    int t = threadIdx.x;
    int node0 = blockIdx.x * 32;
    for (int i = t; i < 32 * (D / 4); i += 256) {
        int row = i >> 5;
        int c4 = (i & 31) * 4;
        float4 v = make_float4(0.f, 0.f, 0.f, 0.f);
        if (node0 + row < N_NODES) v = *(const float4*)(in + (size_t)(node0 + row) * D + c4);
        *(float4*)&xs[row][c4] = v;
    }
    __syncthreads();
    int f4 = (t & 63) * 4;   // output feature (0..255 step 4)
    int ng = t >> 6;         // node group (wave id): 8 nodes each
    float4 bb = *(const float4*)(b + f4);
    float acc[8][4];
#pragma unroll
    for (int n8 = 0; n8 < 8; ++n8) { acc[n8][0] = bb.x; acc[n8][1] = bb.y; acc[n8][2] = bb.z; acc[n8][3] = bb.w; }
#pragma unroll 4
    for (int k = 0; k < D; ++k) {
        float4 w = *(const float4*)(W + (size_t)k * TWO_D + f4);
#pragma unroll
        for (int n8 = 0; n8 < 8; ++n8) {
            float x = xs[ng * 8 + n8][k];   // wave-uniform -> LDS broadcast
            acc[n8][0] += x * w.x; acc[n8][1] += x * w.y;
            acc[n8][2] += x * w.z; acc[n8][3] += x * w.w;
        }
    }
#pragma unroll
    for (int n8 = 0; n8 < 8; ++n8) {
        int node = node0 + ng * 8 + n8;
        if (node < N_NODES) {
            float4 o;
            o.x = fmaxf(acc[n8][0], 0.f); o.y = fmaxf(acc[n8][1], 0.f);
            o.z = fmaxf(acc[n8][2], 0.f); o.w = fmaxf(acc[n8][3], 0.f);
            *(float4*)(out + (size_t)node * TWO_D + f4) = o;
        }
    }
}

// h[N,128] = hid[N,256] @ W[256,128] + b (+ res)
__global__ __launch_bounds__(256) void gemm2_kernel(const float* __restrict__ in, const float* __restrict__ W,
                                                    const float* __restrict__ b, const float* __restrict__ res,
                                                    float* __restrict__ out) {
    __shared__ float xs[32][TWO_D];
    int t = threadIdx.x;
    int node0 = blockIdx.x * 32;
    for (int i = t; i < 32 * (TWO_D / 4); i += 256) {
        int row = i >> 6;
        int c4 = (i & 63) * 4;
        float4 v = make_float4(0.f, 0.f, 0.f, 0.f);
        if (node0 + row < N_NODES) v = *(const float4*)(in + (size_t)(node0 + row) * TWO_D + c4);
        *(float4*)&xs[row][c4] = v;
    }
    __syncthreads();
    int f4 = (t & 31) * 4;   // output feature (0..127 step 4)
    int ng = t >> 5;         // node group: 4 nodes each
    float4 bb = *(const float4*)(b + f4);
    float acc[4][4];
#pragma unroll
    for (int n4 = 0; n4 < 4; ++n4) { acc[n4][0] = bb.x; acc[n4][1] = bb.y; acc[n4][2] = bb.z; acc[n4][3] = bb.w; }
#pragma unroll 4
    for (int k = 0; k < TWO_D; ++k) {
        float4 w = *(const float4*)(W + (size_t)k * D + f4);
#pragma unroll
        for (int n4 = 0; n4 < 4; ++n4) {
            float x = xs[ng * 4 + n4][k];   // 2 addrs per wave -> free 2-way
            acc[n4][0] += x * w.x; acc[n4][1] += x * w.y;
            acc[n4][2] += x * w.z; acc[n4][3] += x * w.w;
        }
    }
#pragma unroll
    for (int n4 = 0; n4 < 4; ++n4) {
        int node = node0 + ng * 4 + n4;
        if (node < N_NODES) {
            float4 o;
            o.x = acc[n4][0]; o.y = acc[n4][1]; o.z = acc[n4][2]; o.w = acc[n4][3];
            if (res != nullptr) {
                float4 rv = *(const float4*)(res + (size_t)node * D + f4);
                o.x += rv.x; o.y += rv.y; o.z += rv.z; o.w += rv.w;
            }
            *(float4*)(out + (size_t)node * D + f4) = o;
        }
    }
}

// ---------------- Final LN + ReLU + projection ----------------

__global__ __launch_bounds__(256) void final_kernel(const float* __restrict__ h, const float* __restrict__ scale,
                                                    const float* __restrict__ bias, const float* __restrict__ Wout,
                                                    const float* __restrict__ bout, float* __restrict__ out) {
    int wid = threadIdx.x >> 6, lane = threadIdx.x & 63;
    int row = blockIdx.x * 4 + wid;
    if (row >= N_NODES) return;
    float2 hv = *(const float2*)(h + (size_t)row * D + lane * 2);
    float sum = hv.x + hv.y;
    for (int off = 32; off; off >>= 1) sum += __shfl_xor(sum, off);
    float mu = sum * (1.0f / D);
    float dx = hv.x - mu, dy = hv.y - mu;
    float vs = dx * dx + dy * dy;
    for (int off = 32; off; off >>= 1) vs += __shfl_xor(vs, off);
    float r = rsqrtf(vs * (1.0f / D) + LN_EPS);
    float2 sc = *(const float2*)(scale + lane * 2);
    float2 bi = *(const float2*)(bias + lane * 2);
    float2 wv = *(const float2*)(Wout + lane * 2);
    float y0 = fmaxf(dx * r * sc.x + bi.x, 0.f);
    float y1 = fmaxf(dy * r * sc.y + bi.y, 0.f);
    float dot = y0 * wv.x + y1 * wv.y;
    for (int off = 32; off; off >>= 1) dot += __shfl_xor(dot, off);
    if (lane == 0) out[row] = dot + bout[0];
}

// ---------------- launch ----------------

extern "C" void kernel_launch(void* const* d_in, const int* in_sizes, int n_in,
                              void* d_out, int out_size, void* d_ws, size_t ws_size,
                              hipStream_t stream) {
    const float* x        = (const float*)d_in[0];
    const int*   ei       = (const int*)d_in[1];
    const float* ea       = (const float*)d_in[2];
    const float* ln_scale = (const float*)d_in[3];
    const float* ln_bias  = (const float*)d_in[4];
    const float* W1       = (const float*)d_in[5];
    const float* b1       = (const float*)d_in[6];
    const float* W2       = (const float*)d_in[7];
    const float* b2       = (const float*)d_in[8];
    const float* beta     = (const float*)d_in[9];
    const float* lnf_s    = (const float*)d_in[10];
    const float* lnf_b    = (const float*)d_in[11];
    const float* Wout     = (const float*)d_in[12];
    const float* bout     = (const float*)d_in[13];
    float* out = (float*)d_out;

    char* w = (char*)d_ws;
    float* h   = (float*)w;  w += (size_t)N_NODES * D * 4;       // 25.6 MB
    float* hn  = (float*)w;  w += (size_t)N_NODES * D * 4;       // 25.6 MB
    float* pre = (float*)w;  w += (size_t)N_NODES * D * 4;       // 25.6 MB
    float* hid = (float*)w;  w += (size_t)N_NODES * TWO_D * 4;   // 51.2 MB
    int* deg    = (int*)w;   w += (size_t)N_NODES * 4;
    int* rowptr = (int*)w;   w += (size_t)(N_NODES + 1) * 4;
    int* cursor = (int*)w;   w += (size_t)N_NODES * 4;
    int* eids   = (int*)w;   w += (size_t)N_EDGES * 4;
    int* srcp   = (int*)w;

    hipMemsetAsync(deg, 0, (size_t)N_NODES * 4, stream);
    hipMemsetAsync(cursor, 0, (size_t)N_NODES * 4, stream);
    hist_kernel<<<2048, 256, 0, stream>>>(ei, deg);
    scan_kernel<<<1, 1024, 0, stream>>>(deg, rowptr);
    scatter_kernel<<<2048, 256, 0, stream>>>(ei, rowptr, cursor, eids, srcp);

    const int grid_rows = (N_NODES + 3) / 4;     // 12500
    const int grid_gemm = (N_NODES + 31) / 32;   // 1563

    for (int layer = 0; layer < L; ++layer) {
        const float* hin;
        if (layer == 0) {
            hin = x;
        } else {
            ln_relu_kernel<<<grid_rows, 256, 0, stream>>>(h, ln_scale + (size_t)layer * D,
                                                          ln_bias + (size_t)layer * D, hn);
            hin = hn;
        }
        aggregate_kernel<<<grid_rows, 256, 0, stream>>>(hin, ea, rowptr, eids, srcp, beta, layer, pre);
        gemm1_kernel<<<grid_gemm, 256, 0, stream>>>(pre, W1 + (size_t)layer * D * TWO_D,
                                                    b1 + (size_t)layer * TWO_D, hid);
        gemm2_kernel<<<grid_gemm, 256, 0, stream>>>(hid, W2 + (size_t)layer * TWO_D * D,
                                                    b2 + (size_t)layer * D,
                                                    layer == 0 ? nullptr : h, h);
    }
    final_kernel<<<grid_rows, 256, 0, stream>>>(h, lnf_s, lnf_b, Wout, bout, out);
}

// Round 2
// 1417.184 us; speedup vs baseline: 1.1357x; 1.1357x over previous
//
#include <hip/hip_runtime.h>
#include <hip/hip_bf16.h>
#include <cstddef>

#define N_NODES 50000
#define N_EDGES 1600000
#define D 128
#define TWO_D 256
#define L 3
#define EPS 1e-7f
#define LN_EPS 1e-5f

// ---------------- CSR build ----------------

__global__ __launch_bounds__(256) void hist_kernel(const int* __restrict__ ei, int* __restrict__ deg) {
    int idx = blockIdx.x * blockDim.x + threadIdx.x;
    int stride = gridDim.x * blockDim.x;
    for (int e = idx; e < N_EDGES; e += stride)
        atomicAdd(&deg[ei[N_EDGES + e]], 1);
}

// Hierarchical scan: A) per-block (1024 elems) inclusive scan + block sums,
// B) 1-wave scan of the 49 block sums, C) add offsets, write rowptr, zero cursor.

__global__ __launch_bounds__(256) void scanA_kernel(const int* __restrict__ deg, int* __restrict__ part,
                                                    int* __restrict__ bsum) {
    __shared__ int wsum[4];
    int b = blockIdx.x, t = threadIdx.x;
    int lane = t & 63, wid = t >> 6;
    int base = b * 1024 + t * 4;
    int v0 = 0, v1 = 0, v2 = 0, v3 = 0;
    if (base + 0 < N_NODES) v0 = deg[base + 0];
    if (base + 1 < N_NODES) v1 = deg[base + 1];
    if (base + 2 < N_NODES) v2 = deg[base + 2];
    if (base + 3 < N_NODES) v3 = deg[base + 3];
    int s0 = v0, s1 = s0 + v1, s2 = s1 + v2, s3 = s2 + v3;
    int inc = s3;
    for (int off = 1; off < 64; off <<= 1) {
        int u = __shfl_up(inc, off);
        if (lane >= off) inc += u;
    }
    if (lane == 63) wsum[wid] = inc;
    __syncthreads();
    int woff = 0;
    for (int w = 0; w < wid; ++w) woff += wsum[w];
    int excl = woff + inc - s3;   // exclusive prefix within block
    if (base + 0 < N_NODES) part[base + 0] = excl + s0;
    if (base + 1 < N_NODES) part[base + 1] = excl + s1;
    if (base + 2 < N_NODES) part[base + 2] = excl + s2;
    if (base + 3 < N_NODES) part[base + 3] = excl + s3;
    if (t == 255) bsum[b] = woff + inc;  // block total
}

__global__ __launch_bounds__(64) void scanB_kernel(int* __restrict__ bsum, int nb) {
    int lane = threadIdx.x;
    int v = (lane < nb) ? bsum[lane] : 0;
    int inc = v;
    for (int off = 1; off < 64; off <<= 1) {
        int u = __shfl_up(inc, off);
        if (lane >= off) inc += u;
    }
    if (lane < nb) bsum[lane] = inc - v;  // exclusive block offsets
}

__global__ __launch_bounds__(256) void scanC_kernel(const int* __restrict__ part, const int* __restrict__ bsum,
                                                    int* __restrict__ rowptr, int* __restrict__ cursor) {
    int i = blockIdx.x * blockDim.x + threadIdx.x;
    if (i >= N_NODES) return;
    rowptr[i + 1] = part[i] + bsum[i >> 10];
    cursor[i] = 0;
    if (i == 0) rowptr[0] = 0;
}

__global__ __launch_bounds__(256) void scatter_kernel(const int* __restrict__ ei, const int* __restrict__ rowptr,
                                                      int* __restrict__ cursor, int2* __restrict__ es) {
    int idx = blockIdx.x * blockDim.x + threadIdx.x;
    int stride = gridDim.x * blockDim.x;
    for (int e = idx; e < N_EDGES; e += stride) {
        int dn = ei[N_EDGES + e];
        int pos = atomicAdd(&cursor[dn], 1);
        es[rowptr[dn] + pos] = make_int2(ei[e], e);   // (src, edge_id) one 8B write
    }
}

// ---------------- Softmax aggregation (one wave per dst node) ----------------
// aggr = sum(e*msg)/sum(e), e = exp(beta*msg). Softmax shift-invariance makes
// the segment_max pass unnecessary; msg in [eps, ~12] so exp() is safe in f32.

__global__ __launch_bounds__(256) void aggregate_kernel(const float* __restrict__ hn, const float* __restrict__ ea,
                                                        const int* __restrict__ rowptr, const int2* __restrict__ es,
                                                        const float* __restrict__ beta, int layer,
                                                        float* __restrict__ pre) {
    int wid = threadIdx.x >> 6, lane = threadIdx.x & 63;
    int d = blockIdx.x * 4 + wid;
    if (d >= N_NODES) return;
    float bet = beta[layer];
    int j0 = rowptr[d], j1 = rowptr[d + 1];
    float se0 = 0.f, se1 = 0.f, sm0 = 0.f, sm1 = 0.f;
    int2 p = (j0 < j1) ? es[j0] : make_int2(0, 0);
    for (int j = j0; j < j1; ++j) {
        int2 pn = (j + 1 < j1) ? es[j + 1] : p;   // prefetch next pair
        float2 hv = *(const float2*)(hn + (size_t)p.x * D + lane * 2);
        float2 av = *(const float2*)(ea + (size_t)p.y * D + lane * 2);
        float m0 = fmaxf(hv.x + av.x, 0.f) + EPS;
        float m1 = fmaxf(hv.y + av.y, 0.f) + EPS;
        float e0 = __expf(bet * m0);
        float e1 = __expf(bet * m1);
        se0 += e0; sm0 += e0 * m0;
        se1 += e1; sm1 += e1 * m1;
        p = pn;
    }
    float a0 = se0 > 0.f ? sm0 / se0 : 0.f;
    float a1 = se1 > 0.f ? sm1 / se1 : 0.f;
    float2 hv = *(const float2*)(hn + (size_t)d * D + lane * 2);
    float2 o;
    o.x = hv.x + a0;
    o.y = hv.y + a1;
    *(float2*)(pre + (size_t)d * D + lane * 2) = o;
}

// ---------------- Fused MLP: relu(pre@W1+b1)@W2+b2 (+res), epilogue LN ----------------
// mode 0: h_out = mlp(pre);        hn_out = relu(LN(h_out; ln_s, ln_b))
// mode 1: h_out = mlp(pre) + res;  hn_out = relu(LN(h_out; ln_s, ln_b))
// mode 2: h3 = mlp(pre) + res (not stored); out = relu(LN(h3; ln_s, ln_b)) . Wout + bout

__global__ __launch_bounds__(256) void mlp_kernel(const float* __restrict__ pre,
                                                  const float* __restrict__ W1, const float* __restrict__ b1,
                                                  const float* __restrict__ W2, const float* __restrict__ b2,
                                                  const float* __restrict__ res,
                                                  float* __restrict__ h_out,
                                                  const float* __restrict__ ln_s, const float* __restrict__ ln_b,
                                                  float* __restrict__ hn_out,
                                                  const float* __restrict__ Wout, const float* __restrict__ bout,
                                                  float* __restrict__ out, int mode) {
    __shared__ float xs[32][D];        // 16 KB
    __shared__ float hid[32][TWO_D];   // 32 KB
    int t = threadIdx.x;
    int node0 = blockIdx.x * 32;

    // stage pre tile
    for (int i = t; i < 32 * 32; i += 256) {
        int row = i >> 5, c4 = (i & 31) * 4;
        float4 v = make_float4(0.f, 0.f, 0.f, 0.f);
        if (node0 + row < N_NODES) v = *(const float4*)(pre + (size_t)(node0 + row) * D + c4);
        *(float4*)&xs[row][c4] = v;
    }
    __syncthreads();

    // phase 1: hid = relu(xs @ W1 + b1), LDS-resident
    {
        int f4 = (t & 63) * 4;  // 0..255 step 4
        int ng = t >> 6;        // 8 nodes per wave
        float4 bb = *(const float4*)(b1 + f4);
        float acc[8][4];
#pragma unroll
        for (int n = 0; n < 8; ++n) { acc[n][0] = bb.x; acc[n][1] = bb.y; acc[n][2] = bb.z; acc[n][3] = bb.w; }
        for (int k = 0; k < D; k += 4) {
            float4 w0 = *(const float4*)(W1 + (size_t)(k + 0) * TWO_D + f4);
            float4 w1 = *(const float4*)(W1 + (size_t)(k + 1) * TWO_D + f4);
            float4 w2 = *(const float4*)(W1 + (size_t)(k + 2) * TWO_D + f4);
            float4 w3 = *(const float4*)(W1 + (size_t)(k + 3) * TWO_D + f4);
#pragma unroll
            for (int n = 0; n < 8; ++n) {
                float4 x = *(const float4*)&xs[ng * 8 + n][k];  // wave-uniform -> LDS broadcast
                acc[n][0] += x.x * w0.x + x.y * w1.x + x.z * w2.x + x.w * w3.x;
                acc[n][1] += x.x * w0.y + x.y * w1.y + x.z * w2.y + x.w * w3.y;
                acc[n][2] += x.x * w0.z + x.y * w1.z + x.z * w2.z + x.w * w3.z;
                acc[n][3] += x.x * w0.w + x.y * w1.w + x.z * w2.w + x.w * w3.w;
            }
        }
#pragma unroll
        for (int n = 0; n < 8; ++n) {
            hid[ng * 8 + n][f4 + 0] = fmaxf(acc[n][0], 0.f);
            hid[ng * 8 + n][f4 + 1] = fmaxf(acc[n][1], 0.f);
            hid[ng * 8 + n][f4 + 2] = fmaxf(acc[n][2], 0.f);
            hid[ng * 8 + n][f4 + 3] = fmaxf(acc[n][3], 0.f);
        }
    }
    __syncthreads();

    // phase 2: v = hid @ W2 + b2 (+res), epilogue per mode
    int f4 = (t & 31) * 4;  // 0..127 step 4
    int ng = t >> 5;        // 4 nodes per 32-lane group
    float4 bb = *(const float4*)(b2 + f4);
    float acc[4][4];
#pragma unroll
    for (int n = 0; n < 4; ++n) { acc[n][0] = bb.x; acc[n][1] = bb.y; acc[n][2] = bb.z; acc[n][3] = bb.w; }
    for (int k = 0; k < TWO_D; k += 4) {
        float4 w0 = *(const float4*)(W2 + (size_t)(k + 0) * D + f4);
        float4 w1 = *(const float4*)(W2 + (size_t)(k + 1) * D + f4);
        float4 w2 = *(const float4*)(W2 + (size_t)(k + 2) * D + f4);
        float4 w3 = *(const float4*)(W2 + (size_t)(k + 3) * D + f4);
#pragma unroll
        for (int n = 0; n < 4; ++n) {
            float4 x = *(const float4*)&hid[ng * 4 + n][k];  // 2 addrs/wave -> broadcast
            acc[n][0] += x.x * w0.x + x.y * w1.x + x.z * w2.x + x.w * w3.x;
            acc[n][1] += x.x * w0.y + x.y * w1.y + x.z * w2.y + x.w * w3.y;
            acc[n][2] += x.x * w0.z + x.y * w1.z + x.z * w2.z + x.w * w3.z;
            acc[n][3] += x.x * w0.w + x.y * w1.w + x.z * w2.w + x.w * w3.w;
        }
    }

#pragma unroll 1
    for (int n = 0; n < 4; ++n) {
        int node = node0 + ng * 4 + n;
        bool valid = node < N_NODES;
        float4 v = make_float4(acc[n][0], acc[n][1], acc[n][2], acc[n][3]);
        if (res != nullptr && valid) {
            float4 rv = *(const float4*)(res + (size_t)node * D + f4);
            v.x += rv.x; v.y += rv.y; v.z += rv.z; v.w += rv.w;
        }
        if (mode < 2 && valid) *(float4*)(h_out + (size_t)node * D + f4) = v;

        // LayerNorm over the 128 features (held by 32 lanes x 4)
        float s = v.x + v.y + v.z + v.w;
        for (int off = 16; off; off >>= 1) s += __shfl_xor(s, off);
        float mu = s * (1.0f / D);
        float dx = v.x - mu, dy = v.y - mu, dz = v.z - mu, dw = v.w - mu;
        float vs = dx * dx + dy * dy + dz * dz + dw * dw;
        for (int off = 16; off; off >>= 1) vs += __shfl_xor(vs, off);
        float r = rsqrtf(vs * (1.0f / D) + LN_EPS);
        float4 sc = *(const float4*)(ln_s + f4);
        float4 bi = *(const float4*)(ln_b + f4);
        float y0 = fmaxf(dx * r * sc.x + bi.x, 0.f);
        float y1 = fmaxf(dy * r * sc.y + bi.y, 0.f);
        float y2 = fmaxf(dz * r * sc.z + bi.z, 0.f);
        float y3 = fmaxf(dw * r * sc.w + bi.w, 0.f);
        if (mode < 2) {
            if (valid) {
                float4 o = make_float4(y0, y1, y2, y3);
                *(float4*)(hn_out + (size_t)node * D + f4) = o;
            }
        } else {
            float4 wv = *(const float4*)(Wout + f4);
            float dot = y0 * wv.x + y1 * wv.y + y2 * wv.z + y3 * wv.w;
            for (int off = 16; off; off >>= 1) dot += __shfl_xor(dot, off);
            if ((t & 31) == 0 && valid) out[node] = dot + bout[0];
        }
    }
}

// ---------------- launch ----------------

extern "C" void kernel_launch(void* const* d_in, const int* in_sizes, int n_in,
                              void* d_out, int out_size, void* d_ws, size_t ws_size,
                              hipStream_t stream) {
    const float* x        = (const float*)d_in[0];
    const int*   ei       = (const int*)d_in[1];
    const float* ea       = (const float*)d_in[2];
    const float* ln_scale = (const float*)d_in[3];
    const float* ln_bias  = (const float*)d_in[4];
    const float* W1       = (const float*)d_in[5];
    const float* b1       = (const float*)d_in[6];
    const float* W2       = (const float*)d_in[7];
    const float* b2       = (const float*)d_in[8];
    const float* beta     = (const float*)d_in[9];
    const float* lnf_s    = (const float*)d_in[10];
    const float* lnf_b    = (const float*)d_in[11];
    const float* Wout     = (const float*)d_in[12];
    const float* bout     = (const float*)d_in[13];
    float* out = (float*)d_out;

    char* w = (char*)d_ws;
    float* h   = (float*)w;  w += (size_t)N_NODES * D * 4;       // 25.6 MB
    float* hn  = (float*)w;  w += (size_t)N_NODES * D * 4;       // 25.6 MB
    float* pre = (float*)w;  w += (size_t)N_NODES * D * 4;       // 25.6 MB
    int2* es   = (int2*)w;   w += (size_t)N_EDGES * 8;           // 12.8 MB
    int* deg    = (int*)w;   w += (size_t)N_NODES * 4;
    int* part   = (int*)w;   w += (size_t)50176 * 4;
    int* rowptr = (int*)w;   w += (size_t)(N_NODES + 1) * 4;
    int* cursor = (int*)w;   w += (size_t)N_NODES * 4;
    int* bsum   = (int*)w;   w += (size_t)64 * 4;

    const int NB = (N_NODES + 1023) / 1024;  // 49

    hipMemsetAsync(deg, 0, (size_t)N_NODES * 4, stream);
    hist_kernel<<<2048, 256, 0, stream>>>(ei, deg);
    scanA_kernel<<<NB, 256, 0, stream>>>(deg, part, bsum);
    scanB_kernel<<<1, 64, 0, stream>>>(bsum, NB);
    scanC_kernel<<<(N_NODES + 255) / 256, 256, 0, stream>>>(part, bsum, rowptr, cursor);
    scatter_kernel<<<2048, 256, 0, stream>>>(ei, rowptr, cursor, es);

    const int grid_rows = (N_NODES + 3) / 4;     // 12500
    const int grid_gemm = (N_NODES + 31) / 32;   // 1563

    for (int layer = 0; layer < L; ++layer) {
        const float* hin = (layer == 0) ? x : hn;
        aggregate_kernel<<<grid_rows, 256, 0, stream>>>(hin, ea, rowptr, es, beta, layer, pre);
        if (layer < L - 1) {
            // epilogue LN uses NEXT layer's ln params
            mlp_kernel<<<grid_gemm, 256, 0, stream>>>(pre, W1 + (size_t)layer * D * TWO_D,
                                                      b1 + (size_t)layer * TWO_D,
                                                      W2 + (size_t)layer * TWO_D * D,
                                                      b2 + (size_t)layer * D,
                                                      layer == 0 ? nullptr : h, h,
                                                      ln_scale + (size_t)(layer + 1) * D,
                                                      ln_bias + (size_t)(layer + 1) * D,
                                                      hn, nullptr, nullptr, nullptr,
                                                      layer == 0 ? 0 : 1);
        } else {
            mlp_kernel<<<grid_gemm, 256, 0, stream>>>(pre, W1 + (size_t)layer * D * TWO_D,
                                                      b1 + (size_t)layer * TWO_D,
                                                      W2 + (size_t)layer * TWO_D * D,
                                                      b2 + (size_t)layer * D,
                                                      h, nullptr,
                                                      lnf_s, lnf_b, nullptr,
                                                      Wout, bout, out, 2);
        }
    }
}

// Round 3
// 1398.785 us; speedup vs baseline: 1.1507x; 1.0132x over previous
//
#include <hip/hip_runtime.h>
#include <hip/hip_bf16.h>
#include <cstddef>

#define N_NODES 50000
#define N_EDGES 1600000
#define D 128
#define TWO_D 256
#define L 3
#define EPS 1e-7f
#define LN_EPS 1e-5f

__device__ __forceinline__ unsigned short f2bf(float f) {
    unsigned u = __float_as_uint(f);
    unsigned r = (u + 0x7fffu + ((u >> 16) & 1u)) >> 16;
    return (unsigned short)r;
}
__device__ __forceinline__ float bf2f(unsigned short s) {
    return __uint_as_float(((unsigned)s) << 16);
}

// ---------------- CSR build ----------------

__global__ __launch_bounds__(256) void hist_kernel(const int* __restrict__ ei, int* __restrict__ deg) {
    int idx = blockIdx.x * blockDim.x + threadIdx.x;
    int stride = gridDim.x * blockDim.x;
    for (int e = idx; e < N_EDGES; e += stride)
        atomicAdd(&deg[ei[N_EDGES + e]], 1);
}

__global__ __launch_bounds__(256) void scanA_kernel(const int* __restrict__ deg, int* __restrict__ part,
                                                    int* __restrict__ bsum) {
    __shared__ int wsum[4];
    int b = blockIdx.x, t = threadIdx.x;
    int lane = t & 63, wid = t >> 6;
    int base = b * 1024 + t * 4;
    int v0 = 0, v1 = 0, v2 = 0, v3 = 0;
    if (base + 0 < N_NODES) v0 = deg[base + 0];
    if (base + 1 < N_NODES) v1 = deg[base + 1];
    if (base + 2 < N_NODES) v2 = deg[base + 2];
    if (base + 3 < N_NODES) v3 = deg[base + 3];
    int s0 = v0, s1 = s0 + v1, s2 = s1 + v2, s3 = s2 + v3;
    int inc = s3;
    for (int off = 1; off < 64; off <<= 1) {
        int u = __shfl_up(inc, off);
        if (lane >= off) inc += u;
    }
    if (lane == 63) wsum[wid] = inc;
    __syncthreads();
    int woff = 0;
    for (int w = 0; w < wid; ++w) woff += wsum[w];
    int excl = woff + inc - s3;
    if (base + 0 < N_NODES) part[base + 0] = excl + s0;
    if (base + 1 < N_NODES) part[base + 1] = excl + s1;
    if (base + 2 < N_NODES) part[base + 2] = excl + s2;
    if (base + 3 < N_NODES) part[base + 3] = excl + s3;
    if (t == 255) bsum[b] = woff + inc;
}

__global__ __launch_bounds__(64) void scanB_kernel(int* __restrict__ bsum, int nb) {
    int lane = threadIdx.x;
    int v = (lane < nb) ? bsum[lane] : 0;
    int inc = v;
    for (int off = 1; off < 64; off <<= 1) {
        int u = __shfl_up(inc, off);
        if (lane >= off) inc += u;
    }
    if (lane < nb) bsum[lane] = inc - v;
}

__global__ __launch_bounds__(256) void scanC_kernel(const int* __restrict__ part, const int* __restrict__ bsum,
                                                    int* __restrict__ rowptr, int* __restrict__ cursor) {
    int i = blockIdx.x * blockDim.x + threadIdx.x;
    if (i >= N_NODES) return;
    rowptr[i + 1] = part[i] + bsum[i >> 10];
    cursor[i] = 0;
    if (i == 0) rowptr[0] = 0;
}

// slot[e] = CSR position of edge e (sequential read/write; atomics on cursor)
__global__ __launch_bounds__(256) void scatter_slot_kernel(const int* __restrict__ ei, const int* __restrict__ rowptr,
                                                           int* __restrict__ cursor, int* __restrict__ slot) {
    int idx = blockIdx.x * blockDim.x + threadIdx.x;
    int stride = gridDim.x * blockDim.x;
    for (int e = idx; e < N_EDGES; e += stride) {
        int dn = ei[N_EDGES + e];
        int pos = atomicAdd(&cursor[dn], 1);
        slot[e] = rowptr[dn] + pos;
    }
}

// Permute edge_attr into CSR order, converting to bf16. One wave per edge:
// sequential 512B read, scattered 256B write. Also scatter src node id.
__global__ __launch_bounds__(256) void prep_ea_kernel(const float* __restrict__ ea, const int* __restrict__ ei,
                                                      const int* __restrict__ slot, ushort2* __restrict__ eab,
                                                      int* __restrict__ srcs) {
    int wid = (blockIdx.x * blockDim.x + threadIdx.x) >> 6;
    int lane = threadIdx.x & 63;
    int nw = (gridDim.x * blockDim.x) >> 6;
    for (int e = wid; e < N_EDGES; e += nw) {
        int sl = slot[e];
        float2 v = *(const float2*)(ea + (size_t)e * D + lane * 2);
        ushort2 o;
        o.x = f2bf(v.x);
        o.y = f2bf(v.y);
        eab[(size_t)sl * 64 + lane] = o;
        if (lane == 0) srcs[sl] = ei[e];
    }
}

// x (f32) -> bf16 copy for layer-0 gathers
__global__ __launch_bounds__(256) void x2bf_kernel(const float* __restrict__ x, ushort2* __restrict__ xb) {
    int i = blockIdx.x * blockDim.x + threadIdx.x;   // one float2 per thread
    if (i >= N_NODES * (D / 2)) return;
    float2 v = *(const float2*)(x + (size_t)i * 2);
    ushort2 o;
    o.x = f2bf(v.x);
    o.y = f2bf(v.y);
    xb[i] = o;
}

// ---------------- Softmax aggregation (one wave per dst node) ----------------
// aggr = sum(e*msg)/sum(e), e = exp(beta*msg). Softmax shift-invariance makes
// the segment_max pass unnecessary; msg in [eps, ~12] so exp() is safe in f32.
// Edge stream (eab, srcs) is CSR-ordered -> fully sequential HBM reads.

__global__ __launch_bounds__(256) void aggregate_kernel(const float* __restrict__ resid,
                                                        const ushort2* __restrict__ hnb,
                                                        const ushort2* __restrict__ eab,
                                                        const int* __restrict__ rowptr,
                                                        const int* __restrict__ srcs,
                                                        const float* __restrict__ beta, int layer,
                                                        float* __restrict__ pre) {
    int wid = threadIdx.x >> 6, lane = threadIdx.x & 63;
    int d = blockIdx.x * 4 + wid;
    if (d >= N_NODES) return;
    float bet = beta[layer];
    int j0 = rowptr[d], j1 = rowptr[d + 1];
    float se0 = 0.f, se1 = 0.f, sm0 = 0.f, sm1 = 0.f;
    int j = j0;
    for (; j + 1 < j1; j += 2) {
        int s0 = srcs[j], s1 = srcs[j + 1];
        ushort2 a0 = eab[(size_t)j * 64 + lane];
        ushort2 a1 = eab[(size_t)(j + 1) * 64 + lane];
        ushort2 h0 = hnb[(size_t)s0 * 64 + lane];
        ushort2 h1 = hnb[(size_t)s1 * 64 + lane];
        float m00 = fmaxf(bf2f(h0.x) + bf2f(a0.x), 0.f) + EPS;
        float m01 = fmaxf(bf2f(h0.y) + bf2f(a0.y), 0.f) + EPS;
        float m10 = fmaxf(bf2f(h1.x) + bf2f(a1.x), 0.f) + EPS;
        float m11 = fmaxf(bf2f(h1.y) + bf2f(a1.y), 0.f) + EPS;
        float e00 = __expf(bet * m00);
        float e01 = __expf(bet * m01);
        float e10 = __expf(bet * m10);
        float e11 = __expf(bet * m11);
        se0 += e00 + e10; sm0 += e00 * m00 + e10 * m10;
        se1 += e01 + e11; sm1 += e01 * m01 + e11 * m11;
    }
    if (j < j1) {
        int s0 = srcs[j];
        ushort2 a0 = eab[(size_t)j * 64 + lane];
        ushort2 h0 = hnb[(size_t)s0 * 64 + lane];
        float m00 = fmaxf(bf2f(h0.x) + bf2f(a0.x), 0.f) + EPS;
        float m01 = fmaxf(bf2f(h0.y) + bf2f(a0.y), 0.f) + EPS;
        float e00 = __expf(bet * m00);
        float e01 = __expf(bet * m01);
        se0 += e00; sm0 += e00 * m00;
        se1 += e01; sm1 += e01 * m01;
    }
    float a0 = se0 > 0.f ? sm0 / se0 : 0.f;
    float a1 = se1 > 0.f ? sm1 / se1 : 0.f;
    float2 hv = *(const float2*)(resid + (size_t)d * D + lane * 2);
    float2 o;
    o.x = hv.x + a0;
    o.y = hv.y + a1;
    *(float2*)(pre + (size_t)d * D + lane * 2) = o;
}

// ---------------- Fused MLP: relu(pre@W1+b1)@W2+b2 (+res), epilogue LN ----------------
// mode 0: h_out = mlp(pre);        hn_out = relu(LN(...)), + bf16 copy
// mode 1: h_out = mlp(pre) + res;  hn_out = relu(LN(...)), + bf16 copy
// mode 2: h3 = mlp(pre) + res (not stored); out = relu(LN(h3)) . Wout + bout

__global__ __launch_bounds__(256) void mlp_kernel(const float* __restrict__ pre,
                                                  const float* __restrict__ W1, const float* __restrict__ b1,
                                                  const float* __restrict__ W2, const float* __restrict__ b2,
                                                  const float* __restrict__ res,
                                                  float* __restrict__ h_out,
                                                  const float* __restrict__ ln_s, const float* __restrict__ ln_b,
                                                  float* __restrict__ hn_out, ushort* __restrict__ hnb_out,
                                                  const float* __restrict__ Wout, const float* __restrict__ bout,
                                                  float* __restrict__ out, int mode) {
    __shared__ float xs[32][D];        // 16 KB
    __shared__ float hid[32][TWO_D];   // 32 KB
    int t = threadIdx.x;
    int node0 = blockIdx.x * 32;

    for (int i = t; i < 32 * 32; i += 256) {
        int row = i >> 5, c4 = (i & 31) * 4;
        float4 v = make_float4(0.f, 0.f, 0.f, 0.f);
        if (node0 + row < N_NODES) v = *(const float4*)(pre + (size_t)(node0 + row) * D + c4);
        *(float4*)&xs[row][c4] = v;
    }
    __syncthreads();

    // phase 1: hid = relu(xs @ W1 + b1), LDS-resident
    {
        int f4 = (t & 63) * 4;
        int ng = t >> 6;
        float4 bb = *(const float4*)(b1 + f4);
        float acc[8][4];
#pragma unroll
        for (int n = 0; n < 8; ++n) { acc[n][0] = bb.x; acc[n][1] = bb.y; acc[n][2] = bb.z; acc[n][3] = bb.w; }
        for (int k = 0; k < D; k += 4) {
            float4 w0 = *(const float4*)(W1 + (size_t)(k + 0) * TWO_D + f4);
            float4 w1 = *(const float4*)(W1 + (size_t)(k + 1) * TWO_D + f4);
            float4 w2 = *(const float4*)(W1 + (size_t)(k + 2) * TWO_D + f4);
            float4 w3 = *(const float4*)(W1 + (size_t)(k + 3) * TWO_D + f4);
#pragma unroll
            for (int n = 0; n < 8; ++n) {
                float4 x = *(const float4*)&xs[ng * 8 + n][k];
                acc[n][0] += x.x * w0.x + x.y * w1.x + x.z * w2.x + x.w * w3.x;
                acc[n][1] += x.x * w0.y + x.y * w1.y + x.z * w2.y + x.w * w3.y;
                acc[n][2] += x.x * w0.z + x.y * w1.z + x.z * w2.z + x.w * w3.z;
                acc[n][3] += x.x * w0.w + x.y * w1.w + x.z * w2.w + x.w * w3.w;
            }
        }
#pragma unroll
        for (int n = 0; n < 8; ++n) {
            hid[ng * 8 + n][f4 + 0] = fmaxf(acc[n][0], 0.f);
            hid[ng * 8 + n][f4 + 1] = fmaxf(acc[n][1], 0.f);
            hid[ng * 8 + n][f4 + 2] = fmaxf(acc[n][2], 0.f);
            hid[ng * 8 + n][f4 + 3] = fmaxf(acc[n][3], 0.f);
        }
    }
    __syncthreads();

    // phase 2: v = hid @ W2 + b2 (+res), epilogue per mode
    int f4 = (t & 31) * 4;
    int ng = t >> 5;
    float4 bb = *(const float4*)(b2 + f4);
    float acc[4][4];
#pragma unroll
    for (int n = 0; n < 4; ++n) { acc[n][0] = bb.x; acc[n][1] = bb.y; acc[n][2] = bb.z; acc[n][3] = bb.w; }
    for (int k = 0; k < TWO_D; k += 4) {
        float4 w0 = *(const float4*)(W2 + (size_t)(k + 0) * D + f4);
        float4 w1 = *(const float4*)(W2 + (size_t)(k + 1) * D + f4);
        float4 w2 = *(const float4*)(W2 + (size_t)(k + 2) * D + f4);
        float4 w3 = *(const float4*)(W2 + (size_t)(k + 3) * D + f4);
#pragma unroll
        for (int n = 0; n < 4; ++n) {
            float4 x = *(const float4*)&hid[ng * 4 + n][k];
            acc[n][0] += x.x * w0.x + x.y * w1.x + x.z * w2.x + x.w * w3.x;
            acc[n][1] += x.x * w0.y + x.y * w1.y + x.z * w2.y + x.w * w3.y;
            acc[n][2] += x.x * w0.z + x.y * w1.z + x.z * w2.z + x.w * w3.z;
            acc[n][3] += x.x * w0.w + x.y * w1.w + x.z * w2.w + x.w * w3.w;
        }
    }

#pragma unroll 1
    for (int n = 0; n < 4; ++n) {
        int node = node0 + ng * 4 + n;
        bool valid = node < N_NODES;
        float4 v = make_float4(acc[n][0], acc[n][1], acc[n][2], acc[n][3]);
        if (res != nullptr && valid) {
            float4 rv = *(const float4*)(res + (size_t)node * D + f4);
            v.x += rv.x; v.y += rv.y; v.z += rv.z; v.w += rv.w;
        }
        if (mode < 2 && valid) *(float4*)(h_out + (size_t)node * D + f4) = v;

        float s = v.x + v.y + v.z + v.w;
        for (int off = 16; off; off >>= 1) s += __shfl_xor(s, off);
        float mu = s * (1.0f / D);
        float dx = v.x - mu, dy = v.y - mu, dz = v.z - mu, dw = v.w - mu;
        float vs = dx * dx + dy * dy + dz * dz + dw * dw;
        for (int off = 16; off; off >>= 1) vs += __shfl_xor(vs, off);
        float r = rsqrtf(vs * (1.0f / D) + LN_EPS);
        float4 sc = *(const float4*)(ln_s + f4);
        float4 bi = *(const float4*)(ln_b + f4);
        float y0 = fmaxf(dx * r * sc.x + bi.x, 0.f);
        float y1 = fmaxf(dy * r * sc.y + bi.y, 0.f);
        float y2 = fmaxf(dz * r * sc.z + bi.z, 0.f);
        float y3 = fmaxf(dw * r * sc.w + bi.w, 0.f);
        if (mode < 2) {
            if (valid) {
                *(float4*)(hn_out + (size_t)node * D + f4) = make_float4(y0, y1, y2, y3);
                ushort4 hb;
                hb.x = f2bf(y0); hb.y = f2bf(y1); hb.z = f2bf(y2); hb.w = f2bf(y3);
                *(ushort4*)(hnb_out + (size_t)node * D + f4) = hb;
            }
        } else {
            float4 wv = *(const float4*)(Wout + f4);
            float dot = y0 * wv.x + y1 * wv.y + y2 * wv.z + y3 * wv.w;
            for (int off = 16; off; off >>= 1) dot += __shfl_xor(dot, off);
            if ((t & 31) == 0 && valid) out[node] = dot + bout[0];
        }
    }
}

// ---------------- launch ----------------

extern "C" void kernel_launch(void* const* d_in, const int* in_sizes, int n_in,
                              void* d_out, int out_size, void* d_ws, size_t ws_size,
                              hipStream_t stream) {
    const float* x        = (const float*)d_in[0];
    const int*   ei       = (const int*)d_in[1];
    const float* ea       = (const float*)d_in[2];
    const float* ln_scale = (const float*)d_in[3];
    const float* ln_bias  = (const float*)d_in[4];
    const float* W1       = (const float*)d_in[5];
    const float* b1       = (const float*)d_in[6];
    const float* W2       = (const float*)d_in[7];
    const float* b2       = (const float*)d_in[8];
    const float* beta     = (const float*)d_in[9];
    const float* lnf_s    = (const float*)d_in[10];
    const float* lnf_b    = (const float*)d_in[11];
    const float* Wout     = (const float*)d_in[12];
    const float* bout     = (const float*)d_in[13];
    float* out = (float*)d_out;

    char* w = (char*)d_ws;
    float*   h      = (float*)w;   w += (size_t)N_NODES * D * 4;        // 25.6 MB
    float*   hn     = (float*)w;   w += (size_t)N_NODES * D * 4;        // 25.6 MB
    float*   pre    = (float*)w;   w += (size_t)N_NODES * D * 4;        // 25.6 MB
    ushort2* hnb    = (ushort2*)w; w += (size_t)N_NODES * D * 2;        // 12.8 MB
    ushort2* xb     = (ushort2*)w; w += (size_t)N_NODES * D * 2;        // 12.8 MB
    ushort2* eab    = (ushort2*)w; w += (size_t)N_EDGES * D * 2;        // 409.6 MB
    int* slot   = (int*)w;   w += (size_t)N_EDGES * 4;                  // 6.4 MB
    int* srcs   = (int*)w;   w += (size_t)N_EDGES * 4;                  // 6.4 MB
    int* deg    = (int*)w;   w += (size_t)N_NODES * 4;
    int* part   = (int*)w;   w += (size_t)50176 * 4;
    int* rowptr = (int*)w;   w += (size_t)(N_NODES + 1) * 4;
    int* cursor = (int*)w;   w += (size_t)N_NODES * 4;
    int* bsum   = (int*)w;   w += (size_t)64 * 4;

    const int NB = (N_NODES + 1023) / 1024;  // 49

    hipMemsetAsync(deg, 0, (size_t)N_NODES * 4, stream);
    hist_kernel<<<2048, 256, 0, stream>>>(ei, deg);
    scanA_kernel<<<NB, 256, 0, stream>>>(deg, part, bsum);
    scanB_kernel<<<1, 64, 0, stream>>>(bsum, NB);
    scanC_kernel<<<(N_NODES + 255) / 256, 256, 0, stream>>>(part, bsum, rowptr, cursor);
    scatter_slot_kernel<<<2048, 256, 0, stream>>>(ei, rowptr, cursor, slot);
    prep_ea_kernel<<<4096, 256, 0, stream>>>(ea, ei, slot, eab, srcs);
    x2bf_kernel<<<(N_NODES * (D / 2) + 255) / 256, 256, 0, stream>>>(x, xb);

    const int grid_rows = (N_NODES + 3) / 4;     // 12500
    const int grid_gemm = (N_NODES + 31) / 32;   // 1563

    for (int layer = 0; layer < L; ++layer) {
        const float*   resid = (layer == 0) ? x : hn;
        const ushort2* gatherb = (layer == 0) ? xb : hnb;
        aggregate_kernel<<<grid_rows, 256, 0, stream>>>(resid, gatherb, eab, rowptr, srcs, beta, layer, pre);
        if (layer < L - 1) {
            mlp_kernel<<<grid_gemm, 256, 0, stream>>>(pre, W1 + (size_t)layer * D * TWO_D,
                                                      b1 + (size_t)layer * TWO_D,
                                                      W2 + (size_t)layer * TWO_D * D,
                                                      b2 + (size_t)layer * D,
                                                      layer == 0 ? nullptr : h, h,
                                                      ln_scale + (size_t)(layer + 1) * D,
                                                      ln_bias + (size_t)(layer + 1) * D,
                                                      hn, (ushort*)hnb, nullptr, nullptr, nullptr,
                                                      layer == 0 ? 0 : 1);
        } else {
            mlp_kernel<<<grid_gemm, 256, 0, stream>>>(pre, W1 + (size_t)layer * D * TWO_D,
                                                      b1 + (size_t)layer * TWO_D,
                                                      W2 + (size_t)layer * TWO_D * D,
                                                      b2 + (size_t)layer * D,
                                                      h, nullptr,
                                                      lnf_s, lnf_b, nullptr, nullptr,
                                                      Wout, bout, out, 2);
        }
    }
}

// Round 4
// 1279.620 us; speedup vs baseline: 1.2578x; 1.0931x over previous
//
#include <hip/hip_runtime.h>
#include <hip/hip_bf16.h>
#include <cstddef>

#define N_NODES 50000
#define N_EDGES 1600000
#define D 128
#define TWO_D 256
#define L 3
#define EPS 1e-7f
#define LN_EPS 1e-5f

__device__ __forceinline__ unsigned short f2bf(float f) {
    unsigned u = __float_as_uint(f);
    unsigned r = (u + 0x7fffu + ((u >> 16) & 1u)) >> 16;
    return (unsigned short)r;
}
__device__ __forceinline__ float bf2f(unsigned short s) {
    return __uint_as_float(((unsigned)s) << 16);
}
// packed-bf16 expand: low half / high half of a uint
__device__ __forceinline__ float bflo(unsigned u) { return __uint_as_float(u << 16); }
__device__ __forceinline__ float bfhi(unsigned u) { return __uint_as_float(u & 0xffff0000u); }

// ---------------- CSR build ----------------

__global__ __launch_bounds__(256) void hist_kernel(const int* __restrict__ ei, int* __restrict__ deg) {
    int idx = blockIdx.x * blockDim.x + threadIdx.x;
    int stride = gridDim.x * blockDim.x;
    for (int e = idx; e < N_EDGES; e += stride)
        atomicAdd(&deg[ei[N_EDGES + e]], 1);
}

__global__ __launch_bounds__(256) void scanA_kernel(const int* __restrict__ deg, int* __restrict__ part,
                                                    int* __restrict__ bsum) {
    __shared__ int wsum[4];
    int b = blockIdx.x, t = threadIdx.x;
    int lane = t & 63, wid = t >> 6;
    int base = b * 1024 + t * 4;
    int v0 = 0, v1 = 0, v2 = 0, v3 = 0;
    if (base + 0 < N_NODES) v0 = deg[base + 0];
    if (base + 1 < N_NODES) v1 = deg[base + 1];
    if (base + 2 < N_NODES) v2 = deg[base + 2];
    if (base + 3 < N_NODES) v3 = deg[base + 3];
    int s0 = v0, s1 = s0 + v1, s2 = s1 + v2, s3 = s2 + v3;
    int inc = s3;
    for (int off = 1; off < 64; off <<= 1) {
        int u = __shfl_up(inc, off);
        if (lane >= off) inc += u;
    }
    if (lane == 63) wsum[wid] = inc;
    __syncthreads();
    int woff = 0;
    for (int w = 0; w < wid; ++w) woff += wsum[w];
    int excl = woff + inc - s3;
    if (base + 0 < N_NODES) part[base + 0] = excl + s0;
    if (base + 1 < N_NODES) part[base + 1] = excl + s1;
    if (base + 2 < N_NODES) part[base + 2] = excl + s2;
    if (base + 3 < N_NODES) part[base + 3] = excl + s3;
    if (t == 255) bsum[b] = woff + inc;
}

__global__ __launch_bounds__(64) void scanB_kernel(int* __restrict__ bsum, int nb) {
    int lane = threadIdx.x;
    int v = (lane < nb) ? bsum[lane] : 0;
    int inc = v;
    for (int off = 1; off < 64; off <<= 1) {
        int u = __shfl_up(inc, off);
        if (lane >= off) inc += u;
    }
    if (lane < nb) bsum[lane] = inc - v;
}

__global__ __launch_bounds__(256) void scanC_kernel(const int* __restrict__ part, const int* __restrict__ bsum,
                                                    int* __restrict__ rowptr, int* __restrict__ cursor) {
    int i = blockIdx.x * blockDim.x + threadIdx.x;
    if (i >= N_NODES) return;
    rowptr[i + 1] = part[i] + bsum[i >> 10];
    cursor[i] = 0;
    if (i == 0) rowptr[0] = 0;
}

__global__ __launch_bounds__(256) void scatter_slot_kernel(const int* __restrict__ ei, const int* __restrict__ rowptr,
                                                           int* __restrict__ cursor, int* __restrict__ slot) {
    int idx = blockIdx.x * blockDim.x + threadIdx.x;
    int stride = gridDim.x * blockDim.x;
    for (int e = idx; e < N_EDGES; e += stride) {
        int dn = ei[N_EDGES + e];
        int pos = atomicAdd(&cursor[dn], 1);
        slot[e] = rowptr[dn] + pos;
    }
}

// Permute edge_attr into CSR order as bf16; scatter src ids.
__global__ __launch_bounds__(256) void prep_ea_kernel(const float* __restrict__ ea, const int* __restrict__ ei,
                                                      const int* __restrict__ slot, ushort2* __restrict__ eab,
                                                      int* __restrict__ srcs) {
    int wid = (blockIdx.x * blockDim.x + threadIdx.x) >> 6;
    int lane = threadIdx.x & 63;
    int nw = (gridDim.x * blockDim.x) >> 6;
    for (int e = wid; e < N_EDGES; e += nw) {
        int sl = slot[e];
        float2 v = *(const float2*)(ea + (size_t)e * D + lane * 2);
        ushort2 o;
        o.x = f2bf(v.x);
        o.y = f2bf(v.y);
        eab[(size_t)sl * 64 + lane] = o;
        if (lane == 0) srcs[sl] = ei[e];
    }
}

__global__ __launch_bounds__(256) void x2bf_kernel(const float* __restrict__ x, ushort2* __restrict__ xb) {
    int i = blockIdx.x * blockDim.x + threadIdx.x;
    if (i >= N_NODES * (D / 2)) return;
    float2 v = *(const float2*)(x + (size_t)i * 2);
    ushort2 o;
    o.x = f2bf(v.x);
    o.y = f2bf(v.y);
    xb[i] = o;
}

// ---------------- Softmax aggregation: 8 edges x 8 feature-blocks per wave ----------------
// aggr = sum(e*msg)/sum(e), e = exp(beta*msg); shift-invariance removes the max pass.
// Lane = (e8, f8): e8 = lane>>3 edge slot, f8 = lane&7 -> 16 features.
// 8 concurrent gathers/wave + batch-loaded srcs (shfl-distributed) for MLP.

__global__ __launch_bounds__(256) void aggregate_kernel(const float* __restrict__ resid,
                                                        const uint4* __restrict__ hnb,
                                                        const uint4* __restrict__ eab,
                                                        const int* __restrict__ rowptr,
                                                        const int* __restrict__ srcs,
                                                        const float* __restrict__ beta, int layer,
                                                        float* __restrict__ pre) {
    int wid = threadIdx.x >> 6, lane = threadIdx.x & 63;
    int d = blockIdx.x * 4 + wid;
    if (d >= N_NODES) return;
    int e8 = lane >> 3;
    int f8 = lane & 7;
    float bet = beta[layer];
    int j0 = rowptr[d], j1 = rowptr[d + 1];
    int deg = j1 - j0;

    float se[16], sm[16];
#pragma unroll
    for (int i = 0; i < 16; ++i) { se[i] = 0.f; sm[i] = 0.f; }

    if (deg > 0) {
        // batch-load up to 64 src ids for this row (one coalesced load)
        int msrc = (j0 + lane < j1) ? srcs[j0 + lane] : 0;
        bool small = (deg <= 64);
#pragma unroll 2
        for (int j = j0; j < j1; j += 8) {
            int e = j + e8;
            bool valid = e < j1;
            int ec = valid ? e : j1 - 1;      // clamp to stay in-bounds
            int s;
            if (small) s = __shfl(msrc, ec - j0);
            else       s = srcs[ec];
            // 16 features = 2 x uint4 (8 bf16 each)
            uint4 a0 = eab[(size_t)ec * 16 + f8 * 2 + 0];
            uint4 a1 = eab[(size_t)ec * 16 + f8 * 2 + 1];
            uint4 h0 = hnb[(size_t)s * 16 + f8 * 2 + 0];
            uint4 h1 = hnb[(size_t)s * 16 + f8 * 2 + 1];
            float vm = valid ? 1.f : 0.f;
            const unsigned* au = (const unsigned*)&a0;
            const unsigned* hu = (const unsigned*)&h0;
#pragma unroll
            for (int q = 0; q < 4; ++q) {
                float m0 = fmaxf(bflo(hu[q]) + bflo(au[q]), 0.f) + EPS;
                float m1 = fmaxf(bfhi(hu[q]) + bfhi(au[q]), 0.f) + EPS;
                float ee0 = __expf(bet * m0) * vm;
                float ee1 = __expf(bet * m1) * vm;
                se[q * 2 + 0] += ee0; sm[q * 2 + 0] = fmaf(ee0, m0, sm[q * 2 + 0]);
                se[q * 2 + 1] += ee1; sm[q * 2 + 1] = fmaf(ee1, m1, sm[q * 2 + 1]);
            }
            const unsigned* av = (const unsigned*)&a1;
            const unsigned* hv = (const unsigned*)&h1;
#pragma unroll
            for (int q = 0; q < 4; ++q) {
                float m0 = fmaxf(bflo(hv[q]) + bflo(av[q]), 0.f) + EPS;
                float m1 = fmaxf(bfhi(hv[q]) + bfhi(av[q]), 0.f) + EPS;
                float ee0 = __expf(bet * m0) * vm;
                float ee1 = __expf(bet * m1) * vm;
                se[8 + q * 2 + 0] += ee0; sm[8 + q * 2 + 0] = fmaf(ee0, m0, sm[8 + q * 2 + 0]);
                se[8 + q * 2 + 1] += ee1; sm[8 + q * 2 + 1] = fmaf(ee1, m1, sm[8 + q * 2 + 1]);
            }
        }
    }

    // reduce over e8 (lane bits 3..5)
#pragma unroll
    for (int off = 8; off < 64; off <<= 1) {
#pragma unroll
        for (int i = 0; i < 16; ++i) {
            se[i] += __shfl_xor(se[i], off);
            sm[i] += __shfl_xor(sm[i], off);
        }
    }

    if (e8 == 0) {
        const float* rrow = resid + (size_t)d * D + f8 * 16;
        float* prow = pre + (size_t)d * D + f8 * 16;
#pragma unroll
        for (int q = 0; q < 4; ++q) {
            float4 rv = *(const float4*)(rrow + q * 4);
            float4 o;
            o.x = rv.x + (se[q * 4 + 0] > 0.f ? sm[q * 4 + 0] / se[q * 4 + 0] : 0.f);
            o.y = rv.y + (se[q * 4 + 1] > 0.f ? sm[q * 4 + 1] / se[q * 4 + 1] : 0.f);
            o.z = rv.z + (se[q * 4 + 2] > 0.f ? sm[q * 4 + 2] / se[q * 4 + 2] : 0.f);
            o.w = rv.w + (se[q * 4 + 3] > 0.f ? sm[q * 4 + 3] / se[q * 4 + 3] : 0.f);
            *(float4*)(prow + q * 4) = o;
        }
    }
}

// ---------------- Fused MLP: relu(pre@W1+b1)@W2+b2 (+res), epilogue LN ----------------

__global__ __launch_bounds__(256) void mlp_kernel(const float* __restrict__ pre,
                                                  const float* __restrict__ W1, const float* __restrict__ b1,
                                                  const float* __restrict__ W2, const float* __restrict__ b2,
                                                  const float* __restrict__ res,
                                                  float* __restrict__ h_out,
                                                  const float* __restrict__ ln_s, const float* __restrict__ ln_b,
                                                  float* __restrict__ hn_out, ushort* __restrict__ hnb_out,
                                                  const float* __restrict__ Wout, const float* __restrict__ bout,
                                                  float* __restrict__ out, int mode) {
    __shared__ float xs[32][D];
    __shared__ float hid[32][TWO_D];
    int t = threadIdx.x;
    int node0 = blockIdx.x * 32;

    for (int i = t; i < 32 * 32; i += 256) {
        int row = i >> 5, c4 = (i & 31) * 4;
        float4 v = make_float4(0.f, 0.f, 0.f, 0.f);
        if (node0 + row < N_NODES) v = *(const float4*)(pre + (size_t)(node0 + row) * D + c4);
        *(float4*)&xs[row][c4] = v;
    }
    __syncthreads();

    {
        int f4 = (t & 63) * 4;
        int ng = t >> 6;
        float4 bb = *(const float4*)(b1 + f4);
        float acc[8][4];
#pragma unroll
        for (int n = 0; n < 8; ++n) { acc[n][0] = bb.x; acc[n][1] = bb.y; acc[n][2] = bb.z; acc[n][3] = bb.w; }
        for (int k = 0; k < D; k += 4) {
            float4 w0 = *(const float4*)(W1 + (size_t)(k + 0) * TWO_D + f4);
            float4 w1 = *(const float4*)(W1 + (size_t)(k + 1) * TWO_D + f4);
            float4 w2 = *(const float4*)(W1 + (size_t)(k + 2) * TWO_D + f4);
            float4 w3 = *(const float4*)(W1 + (size_t)(k + 3) * TWO_D + f4);
#pragma unroll
            for (int n = 0; n < 8; ++n) {
                float4 x = *(const float4*)&xs[ng * 8 + n][k];
                acc[n][0] += x.x * w0.x + x.y * w1.x + x.z * w2.x + x.w * w3.x;
                acc[n][1] += x.x * w0.y + x.y * w1.y + x.z * w2.y + x.w * w3.y;
                acc[n][2] += x.x * w0.z + x.y * w1.z + x.z * w2.z + x.w * w3.z;
                acc[n][3] += x.x * w0.w + x.y * w1.w + x.z * w2.w + x.w * w3.w;
            }
        }
#pragma unroll
        for (int n = 0; n < 8; ++n) {
            hid[ng * 8 + n][f4 + 0] = fmaxf(acc[n][0], 0.f);
            hid[ng * 8 + n][f4 + 1] = fmaxf(acc[n][1], 0.f);
            hid[ng * 8 + n][f4 + 2] = fmaxf(acc[n][2], 0.f);
            hid[ng * 8 + n][f4 + 3] = fmaxf(acc[n][3], 0.f);
        }
    }
    __syncthreads();

    int f4 = (t & 31) * 4;
    int ng = t >> 5;
    float4 bb = *(const float4*)(b2 + f4);
    float acc[4][4];
#pragma unroll
    for (int n = 0; n < 4; ++n) { acc[n][0] = bb.x; acc[n][1] = bb.y; acc[n][2] = bb.z; acc[n][3] = bb.w; }
    for (int k = 0; k < TWO_D; k += 4) {
        float4 w0 = *(const float4*)(W2 + (size_t)(k + 0) * D + f4);
        float4 w1 = *(const float4*)(W2 + (size_t)(k + 1) * D + f4);
        float4 w2 = *(const float4*)(W2 + (size_t)(k + 2) * D + f4);
        float4 w3 = *(const float4*)(W2 + (size_t)(k + 3) * D + f4);
#pragma unroll
        for (int n = 0; n < 4; ++n) {
            float4 x = *(const float4*)&hid[ng * 4 + n][k];
            acc[n][0] += x.x * w0.x + x.y * w1.x + x.z * w2.x + x.w * w3.x;
            acc[n][1] += x.x * w0.y + x.y * w1.y + x.z * w2.y + x.w * w3.y;
            acc[n][2] += x.x * w0.z + x.y * w1.z + x.z * w2.z + x.w * w3.z;
            acc[n][3] += x.x * w0.w + x.y * w1.w + x.z * w2.w + x.w * w3.w;
        }
    }

#pragma unroll 1
    for (int n = 0; n < 4; ++n) {
        int node = node0 + ng * 4 + n;
        bool valid = node < N_NODES;
        float4 v = make_float4(acc[n][0], acc[n][1], acc[n][2], acc[n][3]);
        if (res != nullptr && valid) {
            float4 rv = *(const float4*)(res + (size_t)node * D + f4);
            v.x += rv.x; v.y += rv.y; v.z += rv.z; v.w += rv.w;
        }
        if (mode < 2 && valid) *(float4*)(h_out + (size_t)node * D + f4) = v;

        float s = v.x + v.y + v.z + v.w;
        for (int off = 16; off; off >>= 1) s += __shfl_xor(s, off);
        float mu = s * (1.0f / D);
        float dx = v.x - mu, dy = v.y - mu, dz = v.z - mu, dw = v.w - mu;
        float vs = dx * dx + dy * dy + dz * dz + dw * dw;
        for (int off = 16; off; off >>= 1) vs += __shfl_xor(vs, off);
        float r = rsqrtf(vs * (1.0f / D) + LN_EPS);
        float4 sc = *(const float4*)(ln_s + f4);
        float4 bi = *(const float4*)(ln_b + f4);
        float y0 = fmaxf(dx * r * sc.x + bi.x, 0.f);
        float y1 = fmaxf(dy * r * sc.y + bi.y, 0.f);
        float y2 = fmaxf(dz * r * sc.z + bi.z, 0.f);
        float y3 = fmaxf(dw * r * sc.w + bi.w, 0.f);
        if (mode < 2) {
            if (valid) {
                *(float4*)(hn_out + (size_t)node * D + f4) = make_float4(y0, y1, y2, y3);
                ushort4 hb;
                hb.x = f2bf(y0); hb.y = f2bf(y1); hb.z = f2bf(y2); hb.w = f2bf(y3);
                *(ushort4*)(hnb_out + (size_t)node * D + f4) = hb;
            }
        } else {
            float4 wv = *(const float4*)(Wout + f4);
            float dot = y0 * wv.x + y1 * wv.y + y2 * wv.z + y3 * wv.w;
            for (int off = 16; off; off >>= 1) dot += __shfl_xor(dot, off);
            if ((t & 31) == 0 && valid) out[node] = dot + bout[0];
        }
    }
}

// ---------------- launch ----------------

extern "C" void kernel_launch(void* const* d_in, const int* in_sizes, int n_in,
                              void* d_out, int out_size, void* d_ws, size_t ws_size,
                              hipStream_t stream) {
    const float* x        = (const float*)d_in[0];
    const int*   ei       = (const int*)d_in[1];
    const float* ea       = (const float*)d_in[2];
    const float* ln_scale = (const float*)d_in[3];
    const float* ln_bias  = (const float*)d_in[4];
    const float* W1       = (const float*)d_in[5];
    const float* b1       = (const float*)d_in[6];
    const float* W2       = (const float*)d_in[7];
    const float* b2       = (const float*)d_in[8];
    const float* beta     = (const float*)d_in[9];
    const float* lnf_s    = (const float*)d_in[10];
    const float* lnf_b    = (const float*)d_in[11];
    const float* Wout     = (const float*)d_in[12];
    const float* bout     = (const float*)d_in[13];
    float* out = (float*)d_out;

    char* w = (char*)d_ws;
    float*   h      = (float*)w;   w += (size_t)N_NODES * D * 4;
    float*   hn     = (float*)w;   w += (size_t)N_NODES * D * 4;
    float*   pre    = (float*)w;   w += (size_t)N_NODES * D * 4;
    ushort2* hnb    = (ushort2*)w; w += (size_t)N_NODES * D * 2;
    ushort2* xb     = (ushort2*)w; w += (size_t)N_NODES * D * 2;
    ushort2* eab    = (ushort2*)w; w += (size_t)N_EDGES * D * 2;
    int* slot   = (int*)w;   w += (size_t)N_EDGES * 4;
    int* srcs   = (int*)w;   w += (size_t)N_EDGES * 4;
    int* deg    = (int*)w;   w += (size_t)N_NODES * 4;
    int* part   = (int*)w;   w += (size_t)50176 * 4;
    int* rowptr = (int*)w;   w += (size_t)(N_NODES + 1) * 4;
    int* cursor = (int*)w;   w += (size_t)N_NODES * 4;
    int* bsum   = (int*)w;   w += (size_t)64 * 4;

    const int NB = (N_NODES + 1023) / 1024;

    hipMemsetAsync(deg, 0, (size_t)N_NODES * 4, stream);
    hist_kernel<<<2048, 256, 0, stream>>>(ei, deg);
    scanA_kernel<<<NB, 256, 0, stream>>>(deg, part, bsum);
    scanB_kernel<<<1, 64, 0, stream>>>(bsum, NB);
    scanC_kernel<<<(N_NODES + 255) / 256, 256, 0, stream>>>(part, bsum, rowptr, cursor);
    scatter_slot_kernel<<<2048, 256, 0, stream>>>(ei, rowptr, cursor, slot);
    prep_ea_kernel<<<4096, 256, 0, stream>>>(ea, ei, slot, eab, srcs);
    x2bf_kernel<<<(N_NODES * (D / 2) + 255) / 256, 256, 0, stream>>>(x, xb);

    const int grid_rows = (N_NODES + 3) / 4;
    const int grid_gemm = (N_NODES + 31) / 32;

    for (int layer = 0; layer < L; ++layer) {
        const float* resid = (layer == 0) ? x : hn;
        const uint4* gatherb = (const uint4*)((layer == 0) ? xb : hnb);
        aggregate_kernel<<<grid_rows, 256, 0, stream>>>(resid, gatherb, (const uint4*)eab,
                                                        rowptr, srcs, beta, layer, pre);
        if (layer < L - 1) {
            mlp_kernel<<<grid_gemm, 256, 0, stream>>>(pre, W1 + (size_t)layer * D * TWO_D,
                                                      b1 + (size_t)layer * TWO_D,
                                                      W2 + (size_t)layer * TWO_D * D,
                                                      b2 + (size_t)layer * D,
                                                      layer == 0 ? nullptr : h, h,
                                                      ln_scale + (size_t)(layer + 1) * D,
                                                      ln_bias + (size_t)(layer + 1) * D,
                                                      hn, (ushort*)hnb, nullptr, nullptr, nullptr,
                                                      layer == 0 ? 0 : 1);
        } else {
            mlp_kernel<<<grid_gemm, 256, 0, stream>>>(pre, W1 + (size_t)layer * D * TWO_D,
                                                      b1 + (size_t)layer * TWO_D,
                                                      W2 + (size_t)layer * TWO_D * D,
                                                      b2 + (size_t)layer * D,
                                                      h, nullptr,
                                                      lnf_s, lnf_b, nullptr, nullptr,
                                                      Wout, bout, out, 2);
        }
    }
}

// Round 5
// 783.029 us; speedup vs baseline: 2.0555x; 1.6342x over previous
//
#include <hip/hip_runtime.h>
#include <hip/hip_bf16.h>
#include <cstddef>

#define N_NODES 50000
#define N_EDGES 1600000
#define D 128
#define TWO_D 256
#define L 3
#define EPS 1e-7f
#define LN_EPS 1e-5f

typedef __attribute__((ext_vector_type(8))) short short8;
typedef __attribute__((ext_vector_type(4))) float f32x4;

__device__ __forceinline__ unsigned short f2bf(float f) {
    unsigned u = __float_as_uint(f);
    unsigned r = (u + 0x7fffu + ((u >> 16) & 1u)) >> 16;
    return (unsigned short)r;
}
__device__ __forceinline__ float bflo(unsigned u) { return __uint_as_float(u << 16); }
__device__ __forceinline__ float bfhi(unsigned u) { return __uint_as_float(u & 0xffff0000u); }
__device__ __forceinline__ unsigned bfpack(float lo, float hi) {
    return (unsigned)f2bf(lo) | ((unsigned)f2bf(hi) << 16);
}

// ---------------- CSR build ----------------

__global__ __launch_bounds__(256) void hist_kernel(const int* __restrict__ ei, int* __restrict__ deg) {
    int idx = blockIdx.x * blockDim.x + threadIdx.x;
    int stride = gridDim.x * blockDim.x;
    for (int e = idx; e < N_EDGES; e += stride)
        atomicAdd(&deg[ei[N_EDGES + e]], 1);
}

__global__ __launch_bounds__(256) void scanA_kernel(const int* __restrict__ deg, int* __restrict__ part,
                                                    int* __restrict__ bsum) {
    __shared__ int wsum[4];
    int b = blockIdx.x, t = threadIdx.x;
    int lane = t & 63, wid = t >> 6;
    int base = b * 1024 + t * 4;
    int v0 = 0, v1 = 0, v2 = 0, v3 = 0;
    if (base + 0 < N_NODES) v0 = deg[base + 0];
    if (base + 1 < N_NODES) v1 = deg[base + 1];
    if (base + 2 < N_NODES) v2 = deg[base + 2];
    if (base + 3 < N_NODES) v3 = deg[base + 3];
    int s0 = v0, s1 = s0 + v1, s2 = s1 + v2, s3 = s2 + v3;
    int inc = s3;
    for (int off = 1; off < 64; off <<= 1) {
        int u = __shfl_up(inc, off);
        if (lane >= off) inc += u;
    }
    if (lane == 63) wsum[wid] = inc;
    __syncthreads();
    int woff = 0;
    for (int w = 0; w < wid; ++w) woff += wsum[w];
    int excl = woff + inc - s3;
    if (base + 0 < N_NODES) part[base + 0] = excl + s0;
    if (base + 1 < N_NODES) part[base + 1] = excl + s1;
    if (base + 2 < N_NODES) part[base + 2] = excl + s2;
    if (base + 3 < N_NODES) part[base + 3] = excl + s3;
    if (t == 255) bsum[b] = woff + inc;
}

__global__ __launch_bounds__(64) void scanB_kernel(int* __restrict__ bsum, int nb) {
    int lane = threadIdx.x;
    int v = (lane < nb) ? bsum[lane] : 0;
    int inc = v;
    for (int off = 1; off < 64; off <<= 1) {
        int u = __shfl_up(inc, off);
        if (lane >= off) inc += u;
    }
    if (lane < nb) bsum[lane] = inc - v;
}

__global__ __launch_bounds__(256) void scanC_kernel(const int* __restrict__ part, const int* __restrict__ bsum,
                                                    int* __restrict__ rowptr, int* __restrict__ cursor) {
    int i = blockIdx.x * blockDim.x + threadIdx.x;
    if (i >= N_NODES) return;
    rowptr[i + 1] = part[i] + bsum[i >> 10];
    cursor[i] = 0;
    if (i == 0) rowptr[0] = 0;
}

// es2[slot] = (src node, edge id), one 8B scattered write per edge
__global__ __launch_bounds__(256) void scatter_kernel(const int* __restrict__ ei, const int* __restrict__ rowptr,
                                                      int* __restrict__ cursor, int2* __restrict__ es2) {
    int idx = blockIdx.x * blockDim.x + threadIdx.x;
    int stride = gridDim.x * blockDim.x;
    for (int e = idx; e < N_EDGES; e += stride) {
        int dn = ei[N_EDGES + e];
        int pos = atomicAdd(&cursor[dn], 1);
        es2[rowptr[dn] + pos] = make_int2(ei[e], e);
    }
}

__global__ __launch_bounds__(256) void x2bf_kernel(const float* __restrict__ x, ushort2* __restrict__ xb) {
    int i = blockIdx.x * blockDim.x + threadIdx.x;
    if (i >= N_NODES * (D / 2)) return;
    float2 v = *(const float2*)(x + (size_t)i * 2);
    ushort2 o;
    o.x = f2bf(v.x);
    o.y = f2bf(v.y);
    xb[i] = o;
}

// Pack W1/W2 (all 3 layers) into bf16 MFMA B-fragment order:
// w1p linear idx = ct*2048 + kk*512 + lane*8 + j  <->  W1[k=kk*32+(lane>>4)*8+j][n=ct*16+(lane&15)]
// w2p linear idx = ct*4096 + kk*512 + lane*8 + j  <->  W2[k=kk*32+(lane>>4)*8+j][n=ct*16+(lane&15)]
__global__ __launch_bounds__(256) void pack_w_kernel(const float* __restrict__ W1, const float* __restrict__ W2,
                                                     ushort* __restrict__ w1p, ushort* __restrict__ w2p) {
    int tid = blockIdx.x * 256 + threadIdx.x;
    if (tid >= 3 * 65536) return;
    int layer = tid >> 16, t2 = tid & 65535;
    if (t2 < 32768) {
        int j = t2 & 7, l = (t2 >> 3) & 63, kk = (t2 >> 9) & 3, ct = t2 >> 11;
        int k = kk * 32 + (l >> 4) * 8 + j, n = ct * 16 + (l & 15);
        w1p[(size_t)layer * 32768 + t2] = f2bf(W1[(size_t)layer * 32768 + k * 256 + n]);
    } else {
        int t3 = t2 - 32768;
        int j = t3 & 7, l = (t3 >> 3) & 63, kk = (t3 >> 9) & 7, ct = t3 >> 12;
        int k = kk * 32 + (l >> 4) * 8 + j, n = ct * 16 + (l & 15);
        w2p[(size_t)layer * 32768 + t3] = f2bf(W2[(size_t)layer * 32768 + k * 128 + n]);
    }
}

// ---------------- Softmax aggregation: 8 edges x 8 feature-blocks per wave ----------------
// PREP=1 (layer 0): reads ea f32 via edge-id gather, writes eab bf16 (CSR order) as side effect.
// PREP=0: reads eab bf16 sequentially.
// Output preb = bf16(resid + aggr); resid read from the same bf16 node table.

template <int PREP>
__global__ __launch_bounds__(256) void aggregate_kernel(const uint4* __restrict__ nodeb,
                                                        const float* __restrict__ ea,
                                                        ushort* __restrict__ eab,
                                                        const int* __restrict__ rowptr,
                                                        const int2* __restrict__ es2,
                                                        const float* __restrict__ beta, int layer,
                                                        ushort* __restrict__ preb) {
    int wid = threadIdx.x >> 6, lane = threadIdx.x & 63;
    int d = blockIdx.x * 4 + wid;
    if (d >= N_NODES) return;
    int e8 = lane >> 3;
    int f8 = lane & 7;
    float bet = beta[layer];
    int j0 = rowptr[d], j1 = rowptr[d + 1];
    int deg = j1 - j0;

    float se[16], sm[16];
#pragma unroll
    for (int i = 0; i < 16; ++i) { se[i] = 0.f; sm[i] = 0.f; }

    if (deg > 0) {
        int2 mp = (j0 + lane < j1) ? es2[j0 + lane] : make_int2(0, 0);
        bool small = (deg <= 64);
#pragma unroll 2
        for (int j = j0; j < j1; j += 8) {
            int e = j + e8;
            bool valid = e < j1;
            int ec = valid ? e : j1 - 1;
            int s, eid;
            if (small) {
                s   = __shfl(mp.x, ec - j0);
                eid = __shfl(mp.y, ec - j0);
            } else {
                int2 p = es2[ec];
                s = p.x; eid = p.y;
            }
            uint4 h0 = nodeb[(size_t)s * 16 + f8 * 2 + 0];
            uint4 h1 = nodeb[(size_t)s * 16 + f8 * 2 + 1];
            const unsigned* hu = (const unsigned*)&h0;
            const unsigned* hv = (const unsigned*)&h1;
            float vm = valid ? 1.f : 0.f;
            float af[16];
            if (PREP) {
                const float* ep = ea + (size_t)eid * D + f8 * 16;
                float4 fa0 = *(const float4*)(ep + 0);
                float4 fa1 = *(const float4*)(ep + 4);
                float4 fa2 = *(const float4*)(ep + 8);
                float4 fa3 = *(const float4*)(ep + 12);
                af[0] = fa0.x; af[1] = fa0.y; af[2] = fa0.z; af[3] = fa0.w;
                af[4] = fa1.x; af[5] = fa1.y; af[6] = fa1.z; af[7] = fa1.w;
                af[8] = fa2.x; af[9] = fa2.y; af[10] = fa2.z; af[11] = fa2.w;
                af[12] = fa3.x; af[13] = fa3.y; af[14] = fa3.z; af[15] = fa3.w;
                if (valid) {
                    uint4 o0, o1;
                    o0.x = bfpack(af[0], af[1]);  o0.y = bfpack(af[2], af[3]);
                    o0.z = bfpack(af[4], af[5]);  o0.w = bfpack(af[6], af[7]);
                    o1.x = bfpack(af[8], af[9]);  o1.y = bfpack(af[10], af[11]);
                    o1.z = bfpack(af[12], af[13]); o1.w = bfpack(af[14], af[15]);
                    uint4* dst = (uint4*)(eab + (size_t)ec * D + f8 * 16);
                    dst[0] = o0;
                    dst[1] = o1;
                }
            } else {
                uint4 a0 = *(const uint4*)(eab + (size_t)ec * D + f8 * 16);
                uint4 a1 = *(const uint4*)(eab + (size_t)ec * D + f8 * 16 + 8);
                const unsigned* au = (const unsigned*)&a0;
                const unsigned* av = (const unsigned*)&a1;
#pragma unroll
                for (int q = 0; q < 4; ++q) {
                    af[q * 2 + 0] = bflo(au[q]); af[q * 2 + 1] = bfhi(au[q]);
                    af[8 + q * 2 + 0] = bflo(av[q]); af[8 + q * 2 + 1] = bfhi(av[q]);
                }
            }
#pragma unroll
            for (int q = 0; q < 4; ++q) {
                float m0 = fmaxf(bflo(hu[q]) + af[q * 2 + 0], 0.f) + EPS;
                float m1 = fmaxf(bfhi(hu[q]) + af[q * 2 + 1], 0.f) + EPS;
                float ee0 = __expf(bet * m0) * vm;
                float ee1 = __expf(bet * m1) * vm;
                se[q * 2 + 0] += ee0; sm[q * 2 + 0] = fmaf(ee0, m0, sm[q * 2 + 0]);
                se[q * 2 + 1] += ee1; sm[q * 2 + 1] = fmaf(ee1, m1, sm[q * 2 + 1]);
            }
#pragma unroll
            for (int q = 0; q < 4; ++q) {
                float m0 = fmaxf(bflo(hv[q]) + af[8 + q * 2 + 0], 0.f) + EPS;
                float m1 = fmaxf(bfhi(hv[q]) + af[8 + q * 2 + 1], 0.f) + EPS;
                float ee0 = __expf(bet * m0) * vm;
                float ee1 = __expf(bet * m1) * vm;
                se[8 + q * 2 + 0] += ee0; sm[8 + q * 2 + 0] = fmaf(ee0, m0, sm[8 + q * 2 + 0]);
                se[8 + q * 2 + 1] += ee1; sm[8 + q * 2 + 1] = fmaf(ee1, m1, sm[8 + q * 2 + 1]);
            }
        }
    }

    // reduce over e8 (lane bits 3..5)
#pragma unroll
    for (int off = 8; off < 64; off <<= 1) {
#pragma unroll
        for (int i = 0; i < 16; ++i) {
            se[i] += __shfl_xor(se[i], off);
            sm[i] += __shfl_xor(sm[i], off);
        }
    }

    if (e8 == 0) {
        uint4 r0 = nodeb[(size_t)d * 16 + f8 * 2 + 0];
        uint4 r1 = nodeb[(size_t)d * 16 + f8 * 2 + 1];
        const unsigned* ru = (const unsigned*)&r0;
        const unsigned* rv = (const unsigned*)&r1;
        float v[16];
#pragma unroll
        for (int q = 0; q < 4; ++q) {
            v[q * 2 + 0] = bflo(ru[q]) + (se[q * 2 + 0] > 0.f ? sm[q * 2 + 0] / se[q * 2 + 0] : 0.f);
            v[q * 2 + 1] = bfhi(ru[q]) + (se[q * 2 + 1] > 0.f ? sm[q * 2 + 1] / se[q * 2 + 1] : 0.f);
            v[8 + q * 2 + 0] = bflo(rv[q]) + (se[8 + q * 2 + 0] > 0.f ? sm[8 + q * 2 + 0] / se[8 + q * 2 + 0] : 0.f);
            v[8 + q * 2 + 1] = bfhi(rv[q]) + (se[8 + q * 2 + 1] > 0.f ? sm[8 + q * 2 + 1] / se[8 + q * 2 + 1] : 0.f);
        }
        uint4 o0, o1;
        o0.x = bfpack(v[0], v[1]);   o0.y = bfpack(v[2], v[3]);
        o0.z = bfpack(v[4], v[5]);   o0.w = bfpack(v[6], v[7]);
        o1.x = bfpack(v[8], v[9]);   o1.y = bfpack(v[10], v[11]);
        o1.z = bfpack(v[12], v[13]); o1.w = bfpack(v[14], v[15]);
        uint4* dst = (uint4*)(preb + (size_t)d * D + f8 * 16);
        dst[0] = o0;
        dst[1] = o1;
    }
}

// ---------------- Fused MFMA MLP: relu(preb@W1+b1)@W2+b2 (+res), epilogue LN ----------------
// Block = 32 nodes, 4 waves. Wave w: row-tile rt=w&1 (16 nodes), col-half ch=w>>1.
// GEMM1: 16x16x32 bf16 MFMA, K=128 (4 steps), 8 col-tiles/wave -> hid (LDS, bf16).
// GEMM2: K=256 (8 steps), 4 col-tiles/wave -> hid2 (LDS, f32) -> LN epilogue.
// mode 0: h=mlp; mode 1: h=mlp+res; both write hnb=bf16(relu(LN)). mode 2: out=relu(LN(mlp+res)).Wout+bout

__global__ __launch_bounds__(256) void mlp_kernel(const ushort* __restrict__ preb,
                                                  const ushort* __restrict__ w1p, const float* __restrict__ b1,
                                                  const ushort* __restrict__ w2p, const float* __restrict__ b2,
                                                  const float* __restrict__ res,
                                                  float* __restrict__ h_out,
                                                  const float* __restrict__ ln_s, const float* __restrict__ ln_b,
                                                  ushort* __restrict__ hnb_out,
                                                  const float* __restrict__ Wout, const float* __restrict__ bout,
                                                  float* __restrict__ out, int mode) {
    __shared__ ushort hid[32][264];   // bf16, +8 pad
    __shared__ float hid2[32][132];   // f32, +4 pad (keeps float4 alignment)
    int t = threadIdx.x;
    int lane = t & 63, w = t >> 6;
    int rt = w & 1, ch = w >> 1;
    int node0 = blockIdx.x * 32;
    int l15 = lane & 15, l4 = lane >> 4;

    // ---- GEMM1 ----
    f32x4 acc[8];
#pragma unroll
    for (int ct = 0; ct < 8; ++ct) {
        float bb = b1[ch * 128 + ct * 16 + l15];
        f32x4 v = {bb, bb, bb, bb};
        acc[ct] = v;
    }
    const ushort* aprow = preb + (size_t)(node0 + rt * 16 + l15) * D + l4 * 8;
    const short8* w1f = (const short8*)w1p;
#pragma unroll
    for (int kk = 0; kk < 4; ++kk) {
        short8 a = *(const short8*)(aprow + kk * 32);
#pragma unroll
        for (int ct = 0; ct < 8; ++ct) {
            int ctg = ch * 8 + ct;
            short8 b = w1f[(ctg * 4 + kk) * 64 + lane];
            acc[ct] = __builtin_amdgcn_mfma_f32_16x16x32_bf16(a, b, acc[ct], 0, 0, 0);
        }
    }
#pragma unroll
    for (int ct = 0; ct < 8; ++ct) {
        int feat = ch * 128 + ct * 16 + l15;
        int row = rt * 16 + l4 * 4;
#pragma unroll
        for (int r = 0; r < 4; ++r)
            hid[row + r][feat] = f2bf(fmaxf(acc[ct][r], 0.f));
    }
    __syncthreads();

    // ---- GEMM2 ----
    f32x4 acc2[4];
#pragma unroll
    for (int ct = 0; ct < 4; ++ct) {
        f32x4 z = {0.f, 0.f, 0.f, 0.f};
        acc2[ct] = z;
    }
    const ushort* ahrow = &hid[rt * 16 + l15][l4 * 8];
    const short8* w2f = (const short8*)w2p;
#pragma unroll
    for (int kk = 0; kk < 8; ++kk) {
        short8 a = *(const short8*)(ahrow + kk * 32);
#pragma unroll
        for (int ct = 0; ct < 4; ++ct) {
            int ctg = ch * 4 + ct;
            short8 b = w2f[(ctg * 8 + kk) * 64 + lane];
            acc2[ct] = __builtin_amdgcn_mfma_f32_16x16x32_bf16(a, b, acc2[ct], 0, 0, 0);
        }
    }
#pragma unroll
    for (int ct = 0; ct < 4; ++ct) {
        int feat = ch * 64 + ct * 16 + l15;
        int row = rt * 16 + l4 * 4;
#pragma unroll
        for (int r = 0; r < 4; ++r)
            hid2[row + r][feat] = acc2[ct][r];
    }
    __syncthreads();

    // ---- epilogue: +b2 (+res), LN, outputs ----
    int f4 = (t & 31) * 4;
    int ng = t >> 5;
    float4 b2v = *(const float4*)(b2 + f4);
#pragma unroll 1
    for (int n = 0; n < 4; ++n) {
        int nl = ng * 4 + n;
        int node = node0 + nl;
        bool valid = node < N_NODES;
        float4 v = *(float4*)&hid2[nl][f4];
        v.x += b2v.x; v.y += b2v.y; v.z += b2v.z; v.w += b2v.w;
        if (res != nullptr && valid) {
            float4 rv = *(const float4*)(res + (size_t)node * D + f4);
            v.x += rv.x; v.y += rv.y; v.z += rv.z; v.w += rv.w;
        }
        if (mode < 2 && valid) *(float4*)(h_out + (size_t)node * D + f4) = v;

        float s = v.x + v.y + v.z + v.w;
        for (int off = 16; off; off >>= 1) s += __shfl_xor(s, off);
        float mu = s * (1.0f / D);
        float dx = v.x - mu, dy = v.y - mu, dz = v.z - mu, dw = v.w - mu;
        float vs = dx * dx + dy * dy + dz * dz + dw * dw;
        for (int off = 16; off; off >>= 1) vs += __shfl_xor(vs, off);
        float r = rsqrtf(vs * (1.0f / D) + LN_EPS);
        float4 sc = *(const float4*)(ln_s + f4);
        float4 bi = *(const float4*)(ln_b + f4);
        float y0 = fmaxf(dx * r * sc.x + bi.x, 0.f);
        float y1 = fmaxf(dy * r * sc.y + bi.y, 0.f);
        float y2 = fmaxf(dz * r * sc.z + bi.z, 0.f);
        float y3 = fmaxf(dw * r * sc.w + bi.w, 0.f);
        if (mode < 2) {
            if (valid) {
                ushort4 hb;
                hb.x = f2bf(y0); hb.y = f2bf(y1); hb.z = f2bf(y2); hb.w = f2bf(y3);
                *(ushort4*)(hnb_out + (size_t)node * D + f4) = hb;
            }
        } else {
            float4 wv = *(const float4*)(Wout + f4);
            float dot = y0 * wv.x + y1 * wv.y + y2 * wv.z + y3 * wv.w;
            for (int off = 16; off; off >>= 1) dot += __shfl_xor(dot, off);
            if ((t & 31) == 0 && valid) out[node] = dot + bout[0];
        }
    }
}

// ---------------- launch ----------------

extern "C" void kernel_launch(void* const* d_in, const int* in_sizes, int n_in,
                              void* d_out, int out_size, void* d_ws, size_t ws_size,
                              hipStream_t stream) {
    const float* x        = (const float*)d_in[0];
    const int*   ei       = (const int*)d_in[1];
    const float* ea       = (const float*)d_in[2];
    const float* ln_scale = (const float*)d_in[3];
    const float* ln_bias  = (const float*)d_in[4];
    const float* W1       = (const float*)d_in[5];
    const float* b1       = (const float*)d_in[6];
    const float* W2       = (const float*)d_in[7];
    const float* b2       = (const float*)d_in[8];
    const float* beta     = (const float*)d_in[9];
    const float* lnf_s    = (const float*)d_in[10];
    const float* lnf_b    = (const float*)d_in[11];
    const float* Wout     = (const float*)d_in[12];
    const float* bout     = (const float*)d_in[13];
    float* out = (float*)d_out;

    char* w = (char*)d_ws;
    float*  h    = (float*)w;  w += (size_t)N_NODES * D * 4;    // 25.6 MB
    ushort* preb = (ushort*)w; w += (size_t)N_NODES * D * 2;    // 12.8 MB
    ushort* hnb  = (ushort*)w; w += (size_t)N_NODES * D * 2;    // 12.8 MB
    ushort* xb   = (ushort*)w; w += (size_t)N_NODES * D * 2;    // 12.8 MB
    ushort* eab  = (ushort*)w; w += (size_t)N_EDGES * D * 2;    // 409.6 MB
    int2* es2   = (int2*)w;  w += (size_t)N_EDGES * 8;          // 12.8 MB
    ushort* w1p = (ushort*)w; w += (size_t)3 * 32768 * 2;
    ushort* w2p = (ushort*)w; w += (size_t)3 * 32768 * 2;
    int* deg    = (int*)w;   w += (size_t)N_NODES * 4;
    int* part   = (int*)w;   w += (size_t)50176 * 4;
    int* rowptr = (int*)w;   w += (size_t)(N_NODES + 1) * 4;
    int* cursor = (int*)w;   w += (size_t)N_NODES * 4;
    int* bsum   = (int*)w;   w += (size_t)64 * 4;

    const int NB = (N_NODES + 1023) / 1024;

    hipMemsetAsync(deg, 0, (size_t)N_NODES * 4, stream);
    hist_kernel<<<2048, 256, 0, stream>>>(ei, deg);
    scanA_kernel<<<NB, 256, 0, stream>>>(deg, part, bsum);
    scanB_kernel<<<1, 64, 0, stream>>>(bsum, NB);
    scanC_kernel<<<(N_NODES + 255) / 256, 256, 0, stream>>>(part, bsum, rowptr, cursor);
    scatter_kernel<<<2048, 256, 0, stream>>>(ei, rowptr, cursor, es2);
    x2bf_kernel<<<(N_NODES * (D / 2) + 255) / 256, 256, 0, stream>>>(x, (ushort2*)xb);
    pack_w_kernel<<<768, 256, 0, stream>>>(W1, W2, w1p, w2p);

    const int grid_rows = (N_NODES + 3) / 4;     // 12500
    const int grid_gemm = (N_NODES + 31) / 32;   // 1563

    for (int layer = 0; layer < L; ++layer) {
        const uint4* nodeb = (const uint4*)((layer == 0) ? xb : hnb);
        if (layer == 0)
            aggregate_kernel<1><<<grid_rows, 256, 0, stream>>>(nodeb, ea, eab, rowptr, es2, beta, layer, preb);
        else
            aggregate_kernel<0><<<grid_rows, 256, 0, stream>>>(nodeb, ea, eab, rowptr, es2, beta, layer, preb);

        if (layer < L - 1) {
            mlp_kernel<<<grid_gemm, 256, 0, stream>>>(preb,
                                                      w1p + (size_t)layer * 32768, b1 + (size_t)layer * TWO_D,
                                                      w2p + (size_t)layer * 32768, b2 + (size_t)layer * D,
                                                      layer == 0 ? nullptr : h, h,
                                                      ln_scale + (size_t)(layer + 1) * D,
                                                      ln_bias + (size_t)(layer + 1) * D,
                                                      hnb, nullptr, nullptr, nullptr, layer == 0 ? 0 : 1);
        } else {
            mlp_kernel<<<grid_gemm, 256, 0, stream>>>(preb,
                                                      w1p + (size_t)layer * 32768, b1 + (size_t)layer * TWO_D,
                                                      w2p + (size_t)layer * 32768, b2 + (size_t)layer * D,
                                                      h, nullptr,
                                                      lnf_s, lnf_b, nullptr,
                                                      Wout, bout, out, 2);
        }
    }
}